// Round 4
// baseline (555.630 us; speedup 1.0000x reference)
//
#include <hip/hip_runtime.h>
#include <math.h>

#define NN 4096
#define KK 32
#define KOb 32
#define BB 2
#define NSLOT 64   // Hbins partial slots (bounds global atomic contention)

constexpr float EPS = 1e-6f;

typedef float nfloat4 __attribute__((ext_vector_type(4)));  // native vec for NT builtins

// ---- workspace layout (in float elements) ----
#define WS_VALS   0                          // B*N*K floats
#define WS_IDX    (WS_VALS + BB*NN*KK)       // B*N*K ints
#define WS_HBP    (WS_IDX + BB*NN*KK)        // B*NSLOT*KO partials (memset 0)
#define WS_CNT    (WS_HBP + BB*NSLOT*KOb)    // 4 floats: [0]=int done-counter (memset 0)
#define WS_TBL    (WS_CNT + 4)               // BB*KO float4: {bx,by,wsoft,wmean}
#define WS_A1     (WS_TBL + BB*KOb*4)        // B*N*K
#define WS_M      (WS_A1 + BB*NN*KK)         // B*N
#define WS_CHI    (WS_M + BB*NN)             // B*N*K
#define WS_A2     (WS_CHI + BB*NN*KK)        // B*N*K
#define WS_SEV    (WS_A2 + BB*NN*KK)         // B*N
#define WS_TEV    (WS_SEV + BB*NN)           // B*N (zeroed in k_row2d)
#define WS_Q      (WS_TEV + BB*NN)           // B*N

// ---- output layout (float elements) ----
#define OUT_A2   0
#define OUT_U    ((size_t)BB*NN*NN)
#define OUT_PSRC (OUT_U + BB*NN)
#define OUT_PTGT (OUT_PSRC + BB*NN)
#define OUT_MAP  (OUT_PTGT + BB*NN)

__device__ __forceinline__ unsigned int fkey(float x) {
    unsigned int u = __float_as_uint(x);
    return u ^ ((unsigned int)((int)u >> 31) | 0x80000000u);
}
__device__ __forceinline__ float key2f(unsigned int k) {
    unsigned int u = (k & 0x80000000u) ? (k ^ 0x80000000u) : ~k;
    return __uint_as_float(u);
}

// =====================================================================
// K1: per-row top-32, ONE 256-thread BLOCK per row. 16 keys/lane in
// registers (nontemporal: A0 is read-once), block threshold search
// (1 barrier/iter via double-buffered counts), prefix compaction,
// wave0 rank-select, fused Hbins. Last block (device atomic
// done-counter; no spin, deadlock-free) reduces HBP and writes the
// Wsoft/Wmean float4 table ONCE.
// =====================================================================
__global__ __launch_bounds__(256) void k_topk(const float* __restrict__ A0,
                                              const float* __restrict__ bins,
                                              float* __restrict__ ws) {
    __shared__ float sbins[2 * KOb];
    __shared__ int   scnt[2][4];
    __shared__ int   swtot[4];
    __shared__ unsigned long long cand[64];
    __shared__ float selv[KK], seldx[KK], seldy[KK];
    __shared__ float shb[KOb];
    __shared__ float sred[64];
    __shared__ int   slast;

    const int t = threadIdx.x;
    const int wv = t >> 6, lane = t & 63;
    const int R = blockIdx.x;
    const int b = R >> 12;
    const int r = R & (NN - 1);

    if (t < 2 * KOb) sbins[t] = bins[t];
    if (t < KOb) shb[t] = 0.f;

    // coalesced: thread t reads float4 #(i*256+t); elem of key[4i+c] = i*1024 + t*4 + c
    const nfloat4* row4 = (const nfloat4*)(A0 + (size_t)R * NN);
    unsigned int key[16];
    #pragma unroll
    for (int i = 0; i < 4; ++i) {
        const nfloat4 f = __builtin_nontemporal_load(row4 + i * 256 + t);
        key[4 * i + 0] = fkey(f.x);
        key[4 * i + 1] = fkey(f.y);
        key[4 * i + 2] = fkey(f.z);
        key[4 * i + 3] = fkey(f.w);
    }

    // ---- block-uniform threshold search: 32 <= count(key > lo) <= 64 ----
    unsigned int lo = 0u, hi = 0xFFFFFFFFu;
    int cnt = NN, it = 0;
    while (cnt > 64) {
        unsigned int mid;
        if (it == 0)      mid = 0xBF7E0000u;   // fkey(0.9921875) ~ E[cnt]=32
        else if (it == 1) mid = 0xBF7C4000u;   // fkey(0.98535)  ~ E[cnt]=60
        else              mid = lo + ((hi - lo) >> 1);
        if (mid <= lo || mid >= hi) mid = lo + ((hi - lo) >> 1);
        if (mid == lo) break;
        int cl = 0;
        #pragma unroll
        for (int j = 0; j < 16; ++j) cl += (key[j] > mid) ? 1 : 0;
        int c = cl;
        #pragma unroll
        for (int m = 32; m >= 1; m >>= 1) c += __shfl_xor(c, m);
        const int p = it & 1;
        if (lane == 0) scnt[p][wv] = c;
        __syncthreads();
        const int ctot = scnt[p][0] + scnt[p][1] + scnt[p][2] + scnt[p][3];
        if (ctot >= KK) { lo = mid; cnt = ctot; } else hi = mid;
        if (++it > 48) break;
    }

    // ---- block prefix compaction of candidates {key > lo} ----
    int cl = 0;
    #pragma unroll
    for (int j = 0; j < 16; ++j) cl += (key[j] > lo) ? 1 : 0;
    int inc = cl;
    #pragma unroll
    for (int m = 1; m < 64; m <<= 1) {
        const int o = __shfl_up(inc, m);
        if (lane >= m) inc += o;
    }
    if (lane == 63) swtot[wv] = inc;
    __syncthreads();
    int off = inc - cl;                        // exclusive within wave
    #pragma unroll
    for (int w = 0; w < 4; ++w) if (w < wv) off += swtot[w];
    const int nc0 = swtot[0] + swtot[1] + swtot[2] + swtot[3];
    const int ncand = (nc0 < 64) ? nc0 : 64;

    int slot = off;
    #pragma unroll
    for (int j = 0; j < 16; ++j) {
        if (key[j] > lo && slot < 64) {
            const unsigned int gidx = (unsigned int)((j >> 2) * 1024 + t * 4 + (j & 3));
            cand[slot] = ((unsigned long long)key[j] << 32)
                       | (unsigned long long)(4095u - gidx);
            ++slot;
        }
    }
    __syncthreads();

    // ---- wave 0: rank selection + emit; packed u64 gives exact tie-break ----
    if (t < 64) {
        const unsigned long long cd = (t < ncand) ? cand[t] : 0ull;
        int rank = 0;
        #pragma unroll
        for (int i = 0; i < 64; ++i) {
            const unsigned long long o = __shfl(cd, i);
            rank += (o > cd) ? 1 : 0;
        }
        if (t < ncand && rank < KK) {
            const float val = key2f((unsigned int)(cd >> 32));
            const int gidx = 4095 - (int)(cd & 0xFFFull);
            ws[WS_VALS + (size_t)R * KK + rank] = val;
            ((int*)(ws + WS_IDX))[(size_t)R * KK + rank] = gidx;
            selv[rank]  = val;
            seldx[rank] = (float)((gidx & 63) - (r & 63));
            seldy[rank] = (float)((gidx >> 6) - (r >> 6));
        }
    }
    __syncthreads();

    // ---- fused Hbins: 32 edges x 32 bins = 1024 tasks over 256 threads ----
    const int e = t >> 3;                       // edge 0..31
    const float v = selv[e], dx0 = seldx[e], dy0 = seldy[e];
    #pragma unroll
    for (int jj = 0; jj < 4; ++jj) {
        const int o = (lane & 7) * 4 + jj;      // bin, constant across xor-8/16/32 group
        const float dx = dx0 - sbins[2 * o], dy = dy0 - sbins[2 * o + 1];
        float contrib = v * __expf(-(dx * dx + dy * dy) * (1.0f / 4.5f));
        contrib += __shfl_xor(contrib, 8);
        contrib += __shfl_xor(contrib, 16);
        contrib += __shfl_xor(contrib, 32);
        if ((lane >> 3) == 0) atomicAdd(&shb[o], contrib);
    }
    __syncthreads();
    if (t < KOb)
        atomicAdd(ws + WS_HBP + b * (NSLOT * KOb) + (R & (NSLOT - 1)) * KOb + t,
                  shb[t]);

    // ---- last-block finalize: reduce HBP -> Wsoft/Wmean float4 table ----
    __syncthreads();                 // compiler drains vmcnt before barrier
    if (t == 0) {
        __threadfence();             // publish this block's HBP adds
        const int old = atomicAdd((int*)(ws + WS_CNT), 1);
        slast = (old == BB * NN - 1) ? 1 : 0;
    }
    __syncthreads();
    if (slast) {
        __threadfence();             // acquire: all blocks' HBP adds visible
        if (t < 64) sred[t] = 0.f;
        __syncthreads();
        {
            const int p = t & 63, g = t >> 6;   // pair p = b*32+o, 4 slot-groups
            const int bb = p >> 5, oo = p & 31;
            const volatile float* hb = ws + WS_HBP + bb * (NSLOT * KOb) + oo;
            float sum = 0.f;
            for (int s = g * 16; s < g * 16 + 16; ++s)
                sum += hb[s * KOb];
            atomicAdd(&sred[p], sum);
        }
        __syncthreads();
        if (t < 64) {
            const int oo = t & 31;
            const float h = 8.0f * sred[t];
            float mx = h;
            #pragma unroll
            for (int m = 16; m >= 1; m >>= 1) mx = fmaxf(mx, __shfl_xor(mx, m));
            const float e2 = __expf(h - mx);
            float ss = e2;
            #pragma unroll
            for (int m = 16; m >= 1; m >>= 1) ss += __shfl_xor(ss, m);
            const float wsf = e2 / ss;
            const float wm = 0.5f * (wsf + __shfl_xor(wsf, 32));
            ((float4*)(ws + WS_TBL))[t] =
                make_float4(sbins[2 * oo], sbins[2 * oo + 1], wsf, wm);
        }
    }
}

// =====================================================================
// K2: per-row R_edges -> A1 -> entropy -> U, m; also chi. Wsoft/Wmean
// table precomputed by k_topk's last block — just load 64 float4s.
// 2 rows per wave (all 64 lanes active).
// =====================================================================
__global__ __launch_bounds__(256) void k_row1(float* __restrict__ ws,
                                              float* __restrict__ out_u) {
    __shared__ float4 stbl[BB * KOb];   // {bin_x, bin_y, wsoft[b][o], wmean[o]}
    const int t = threadIdx.x;
    if (t < BB * KOb) stbl[t] = ((const float4*)(ws + WS_TBL))[t];
    __syncthreads();

    const int wv = t >> 6, lane = t & 63;
    const int half = lane >> 5, k = lane & 31;
    const int R = blockIdx.x * 8 + wv * 2 + half;
    const int b = R >> 12;
    const int r = R & (NN - 1);

    const float val = ws[WS_VALS + (size_t)R * KK + k];
    const int c = ((int*)(ws + WS_IDX))[(size_t)R * KK + k];
    const float dx0 = (float)((c & 63) - (r & 63));
    const float dy0 = (float)((c >> 6) - (r >> 6));
    float racc = 0.f, cacc = 0.f;
    const float4* tb = stbl + (b << 5);
    #pragma unroll
    for (int o = 0; o < KOb; ++o) {
        const float4 cb = tb[o];
        const float dx = dx0 - cb.x, dy = dy0 - cb.y;
        const float kap = __expf(-(dx * dx + dy * dy) * (1.0f / 4.5f));
        racc += cb.z * kap;
        cacc += cb.w * kap;
    }
    const float Redge = 0.001f + racc;
    const float chi = cacc;

    const float tilde = val * Redge;
    float s = tilde;
    #pragma unroll
    for (int m = 16; m >= 1; m >>= 1) s += __shfl_xor(s, m);
    const float a1 = tilde / (s + EPS);

    const float z = 10.f * a1;
    float mz = z;
    #pragma unroll
    for (int m = 16; m >= 1; m >>= 1) mz = fmaxf(mz, __shfl_xor(mz, m));
    const float e = __expf(z - mz);
    float se = e;
    #pragma unroll
    for (int m = 16; m >= 1; m >>= 1) se += __shfl_xor(se, m);
    const float p = e / se;
    const float ent_t = -p * __logf(p + EPS);
    float ent = ent_t;
    #pragma unroll
    for (int m = 16; m >= 1; m >>= 1) ent += __shfl_xor(ent, m);
    const float U = 1.f / (1.f + __expf(ent));

    ws[WS_A1  + (size_t)R * KK + k] = a1;
    ws[WS_CHI + (size_t)R * KK + k] = chi;
    if (k == 0) { out_u[R] = U; ws[WS_M + R] = 1.f - U; }
}

// =====================================================================
// K3: fused row2 + dense write. One block per row: wave 0 does the
// math (hatA -> A2_edges -> dv, q) holding dv,c in regs across the
// zero-fill barrier, scatters directly, whole block streams the dense
// row (nontemporal). Also zero-fills WS_TEV (blocks 0..31).
// =====================================================================
__global__ __launch_bounds__(256) void k_row2d(float* __restrict__ ws,
                                               float* __restrict__ outA2) {
    __shared__ float srow[NN];
    const int R = blockIdx.x;
    const int b = R >> 12;
    const int t = threadIdx.x;

    const int gid = blockIdx.x * 256 + t;
    if (gid < BB * NN) ws[WS_TEV + gid] = 0.f;

    nfloat4* s4 = (nfloat4*)srow;
    const nfloat4 z4 = {0.f, 0.f, 0.f, 0.f};
    #pragma unroll
    for (int i = 0; i < 4; ++i) s4[t + 256 * i] = z4;

    float dvr = 0.f; int cr = -1;
    if (t < 64) {
        const int lane = t;
        const bool act = lane < 32;
        const int k = lane;
        const float mi = ws[WS_M + R];
        float a1 = 0.f; int c = 0; float mj = 0.f;
        if (act) {
            a1 = ws[WS_A1 + (size_t)R * KK + k];
            c = ((int*)(ws + WS_IDX))[(size_t)R * KK + k];
            mj = ws[WS_M + b * NN + c];
        }
        const float hat = act ? mi * a1 * mj : 0.f;
        float S = hat;
        #pragma unroll
        for (int m = 16; m >= 1; m >>= 1) S += __shfl_xor(S, m);
        const float a2e = hat / (S + EPS);
        float S2 = a2e;
        #pragma unroll
        for (int m = 16; m >= 1; m >>= 1) S2 += __shfl_xor(S2, m);
        const float dv = a2e / (S2 + EPS);

        const float z = act ? 8.f * a2e : -1e30f;
        float mz = z;
        #pragma unroll
        for (int m = 16; m >= 1; m >>= 1) mz = fmaxf(mz, __shfl_xor(mz, m));
        const float e = act ? __expf(z - mz) : 0.f;
        float se = e;
        #pragma unroll
        for (int m = 16; m >= 1; m >>= 1) se += __shfl_xor(se, m);
        const float wl = e / se;
        const float chi = act ? ws[WS_CHI + (size_t)R * KK + k] : 0.f;
        float q = act ? wl * chi : 0.f;
        #pragma unroll
        for (int m = 16; m >= 1; m >>= 1) q += __shfl_xor(q, m);
        if (lane == 0) ws[WS_Q + R] = q;

        if (act) {
            ws[WS_A2 + (size_t)R * KK + k] = dv;
            dvr = dv; cr = c;
        }
    }
    __syncthreads();
    if (cr >= 0) srow[cr] = dvr;
    __syncthreads();
    nfloat4* o4 = (nfloat4*)(outA2 + (size_t)R * NN);
    #pragma unroll
    for (int i = 0; i < 4; ++i)
        __builtin_nontemporal_store(s4[t + 256 * i], o4 + t + 256 * i);
}

// =====================================================================
// K4: directional evidence — reverse value found by searching row c's
// 32 indices in the L2-resident edge arrays (2 MB).
// 2 rows per wave — all 64 lanes active.
// =====================================================================
__global__ __launch_bounds__(256) void k_dir(float* __restrict__ ws) {
    const int t = threadIdx.x;
    const int wv = t >> 6, lane = t & 63;
    const int half = lane >> 5, k = lane & 31;
    const int R = blockIdx.x * 8 + wv * 2 + half;
    const int b = R >> 12;
    const int r = R & (NN - 1);

    const float a = ws[WS_A2 + (size_t)R * KK + k];
    const int c = ((int*)(ws + WS_IDX))[(size_t)R * KK + k];
    float pdir = 0.f;
    if (c != r) {
        const int4* irow = (const int4*)((const int*)(ws + WS_IDX)
                                         + (size_t)(b * NN + c) * KK);
        int p = -1;
        #pragma unroll
        for (int q = 0; q < 8; ++q) {
            const int4 i4 = irow[q];
            if (i4.x == r) p = q * 4 + 0;
            if (i4.y == r) p = q * 4 + 1;
            if (i4.z == r) p = q * 4 + 2;
            if (i4.w == r) p = q * 4 + 3;
        }
        const float arev = (p >= 0) ? ws[WS_A2 + (size_t)(b * NN + c) * KK + p] : 0.f;
        const float ef = __expf(8.f * a), er = __expf(8.f * arev);
        pdir = ef / (ef + er + EPS);
    }
    float s = a * pdir;
    #pragma unroll
    for (int m = 16; m >= 1; m >>= 1) s += __shfl_xor(s, m);
    if (k == 0) ws[WS_SEV + R] = s;
    atomicAdd(ws + WS_TEV + b * NN + c, a * (1.f - pdir));
}

// =====================================================================
// K5: fused pi_src/pi_tgt + 5x5 gaussian smoothing + sigmoid.
// =====================================================================
__global__ void k_tail(const float* __restrict__ ws, const float* __restrict__ kern,
                       float* __restrict__ out_psrc, float* __restrict__ out_ptgt,
                       float* __restrict__ out_map) {
    const int i = blockIdx.x * 256 + threadIdx.x;
    const float s = ws[WS_SEV + i], tv = ws[WS_TEV + i];
    const float ps = s / (s + tv + EPS);
    out_psrc[i] = ps;
    out_ptgt[i] = 1.f - ps;

    const int b = i >> 12;
    const int pix = i & 4095;
    const int y = pix >> 6, x = pix & 63;
    float acc = 0.f;
    #pragma unroll
    for (int ky = 0; ky < 5; ++ky) {
        const int yy = y + ky - 2;
        if (yy < 0 || yy >= 64) continue;
        #pragma unroll
        for (int kx = 0; kx < 5; ++kx) {
            const int xx = x + kx - 2;
            if (xx < 0 || xx >= 64) continue;
            acc += ws[WS_Q + b * 4096 + yy * 64 + xx] * kern[ky * 5 + kx];
        }
    }
    out_map[i] = 1.f / (1.f + __expf(-acc));
}

extern "C" void kernel_launch(void* const* d_in, const int* in_sizes, int n_in,
                              void* d_out, int out_size, void* d_ws, size_t ws_size,
                              hipStream_t stream) {
    const float* A0   = (const float*)d_in[1];
    const float* bins = (const float*)d_in[3];
    const float* kern = (const float*)d_in[4];
    float* out = (float*)d_out;
    float* ws  = (float*)d_ws;

    // zero HBP partials + done-counter in one memset
    (void)hipMemsetAsync(ws + WS_HBP, 0, (BB * NSLOT * KOb + 4) * sizeof(float), stream);

    k_topk <<<BB * NN,       256, 0, stream>>>(A0, bins, ws);
    k_row1 <<<BB * NN / 8,   256, 0, stream>>>(ws, out + OUT_U);
    k_row2d<<<BB * NN,       256, 0, stream>>>(ws, out);
    k_dir  <<<BB * NN / 8,   256, 0, stream>>>(ws);
    k_tail <<<BB * NN / 256, 256, 0, stream>>>(ws, kern,
                                               out + OUT_PSRC, out + OUT_PTGT,
                                               out + OUT_MAP);
}

// Round 5
// 286.492 us; speedup vs baseline: 1.9394x; 1.9394x over previous
//
#include <hip/hip_runtime.h>
#include <math.h>

#define NN 4096
#define KK 32
#define KOb 32
#define BB 2
#define NSLOT 64   // Hbins partial slots (bounds global atomic contention)

constexpr float EPS = 1e-6f;

typedef float nfloat4 __attribute__((ext_vector_type(4)));  // native vec for NT builtins

// ---- workspace layout (in float elements) ----
#define WS_VALS   0                          // B*N*K floats
#define WS_IDX    (WS_VALS + BB*NN*KK)       // B*N*K ints
#define WS_HBP    (WS_IDX + BB*NN*KK)        // B*NSLOT*KO partials (memset 0)
#define WS_TBL    (WS_HBP + BB*NSLOT*KOb)    // BB*KO float4: {bx,by,wsoft,wmean}
#define WS_A1     (WS_TBL + BB*KOb*4)        // B*N*K
#define WS_M      (WS_A1 + BB*NN*KK)         // B*N
#define WS_CHI    (WS_M + BB*NN)             // B*N*K
#define WS_A2     (WS_CHI + BB*NN*KK)        // B*N*K
#define WS_SEV    (WS_A2 + BB*NN*KK)         // B*N
#define WS_TEV    (WS_SEV + BB*NN)           // B*N (zeroed in k_row2d)
#define WS_Q      (WS_TEV + BB*NN)           // B*N

// ---- output layout (float elements) ----
#define OUT_A2   0
#define OUT_U    ((size_t)BB*NN*NN)
#define OUT_PSRC (OUT_U + BB*NN)
#define OUT_PTGT (OUT_PSRC + BB*NN)
#define OUT_MAP  (OUT_PTGT + BB*NN)

__device__ __forceinline__ unsigned int fkey(float x) {
    unsigned int u = __float_as_uint(x);
    return u ^ ((unsigned int)((int)u >> 31) | 0x80000000u);
}
__device__ __forceinline__ float key2f(unsigned int k) {
    unsigned int u = (k & 0x80000000u) ? (k ^ 0x80000000u) : ~k;
    return __uint_as_float(u);
}

// =====================================================================
// K1: per-row top-32, ONE 256-thread BLOCK per row. 16 keys/lane in
// registers (nontemporal: A0 is read-once), block threshold search
// (1 barrier/iter via double-buffered counts), prefix compaction,
// wave0 rank-select, fused Hbins. NO per-block device fence/counter
// (R4 lesson: 8192 same-address atomics serialize ≈ +240 µs).
// =====================================================================
__global__ __launch_bounds__(256) void k_topk(const float* __restrict__ A0,
                                              const float* __restrict__ bins,
                                              float* __restrict__ ws) {
    __shared__ float sbins[2 * KOb];
    __shared__ int   scnt[2][4];
    __shared__ int   swtot[4];
    __shared__ unsigned long long cand[64];
    __shared__ float selv[KK], seldx[KK], seldy[KK];
    __shared__ float shb[KOb];

    const int t = threadIdx.x;
    const int wv = t >> 6, lane = t & 63;
    const int R = blockIdx.x;
    const int b = R >> 12;
    const int r = R & (NN - 1);

    if (t < 2 * KOb) sbins[t] = bins[t];
    if (t < KOb) shb[t] = 0.f;

    // coalesced: thread t reads float4 #(i*256+t); elem of key[4i+c] = i*1024 + t*4 + c
    const nfloat4* row4 = (const nfloat4*)(A0 + (size_t)R * NN);
    unsigned int key[16];
    #pragma unroll
    for (int i = 0; i < 4; ++i) {
        const nfloat4 f = __builtin_nontemporal_load(row4 + i * 256 + t);
        key[4 * i + 0] = fkey(f.x);
        key[4 * i + 1] = fkey(f.y);
        key[4 * i + 2] = fkey(f.z);
        key[4 * i + 3] = fkey(f.w);
    }

    // ---- block-uniform threshold search: 32 <= count(key > lo) <= 64 ----
    unsigned int lo = 0u, hi = 0xFFFFFFFFu;
    int cnt = NN, it = 0;
    while (cnt > 64) {
        unsigned int mid;
        if (it == 0)      mid = 0xBF7E0000u;   // fkey(0.9921875) ~ E[cnt]=32
        else if (it == 1) mid = 0xBF7C4000u;   // fkey(0.98535)  ~ E[cnt]=60
        else              mid = lo + ((hi - lo) >> 1);
        if (mid <= lo || mid >= hi) mid = lo + ((hi - lo) >> 1);
        if (mid == lo) break;
        int cl = 0;
        #pragma unroll
        for (int j = 0; j < 16; ++j) cl += (key[j] > mid) ? 1 : 0;
        int c = cl;
        #pragma unroll
        for (int m = 32; m >= 1; m >>= 1) c += __shfl_xor(c, m);
        const int p = it & 1;
        if (lane == 0) scnt[p][wv] = c;
        __syncthreads();
        const int ctot = scnt[p][0] + scnt[p][1] + scnt[p][2] + scnt[p][3];
        if (ctot >= KK) { lo = mid; cnt = ctot; } else hi = mid;
        if (++it > 48) break;
    }

    // ---- block prefix compaction of candidates {key > lo} ----
    int cl = 0;
    #pragma unroll
    for (int j = 0; j < 16; ++j) cl += (key[j] > lo) ? 1 : 0;
    int inc = cl;
    #pragma unroll
    for (int m = 1; m < 64; m <<= 1) {
        const int o = __shfl_up(inc, m);
        if (lane >= m) inc += o;
    }
    if (lane == 63) swtot[wv] = inc;
    __syncthreads();
    int off = inc - cl;                        // exclusive within wave
    #pragma unroll
    for (int w = 0; w < 4; ++w) if (w < wv) off += swtot[w];
    const int nc0 = swtot[0] + swtot[1] + swtot[2] + swtot[3];
    const int ncand = (nc0 < 64) ? nc0 : 64;

    int slot = off;
    #pragma unroll
    for (int j = 0; j < 16; ++j) {
        if (key[j] > lo && slot < 64) {
            const unsigned int gidx = (unsigned int)((j >> 2) * 1024 + t * 4 + (j & 3));
            cand[slot] = ((unsigned long long)key[j] << 32)
                       | (unsigned long long)(4095u - gidx);
            ++slot;
        }
    }
    __syncthreads();

    // ---- wave 0: rank selection + emit; packed u64 gives exact tie-break ----
    if (t < 64) {
        const unsigned long long cd = (t < ncand) ? cand[t] : 0ull;
        int rank = 0;
        #pragma unroll
        for (int i = 0; i < 64; ++i) {
            const unsigned long long o = __shfl(cd, i);
            rank += (o > cd) ? 1 : 0;
        }
        if (t < ncand && rank < KK) {
            const float val = key2f((unsigned int)(cd >> 32));
            const int gidx = 4095 - (int)(cd & 0xFFFull);
            ws[WS_VALS + (size_t)R * KK + rank] = val;
            ((int*)(ws + WS_IDX))[(size_t)R * KK + rank] = gidx;
            selv[rank]  = val;
            seldx[rank] = (float)((gidx & 63) - (r & 63));
            seldy[rank] = (float)((gidx >> 6) - (r >> 6));
        }
    }
    __syncthreads();

    // ---- fused Hbins: 32 edges x 32 bins = 1024 tasks over 256 threads ----
    const int e = t >> 3;                       // edge 0..31
    const float v = selv[e], dx0 = seldx[e], dy0 = seldy[e];
    #pragma unroll
    for (int jj = 0; jj < 4; ++jj) {
        const int o = (lane & 7) * 4 + jj;      // bin, constant across xor-8/16/32 group
        const float dx = dx0 - sbins[2 * o], dy = dy0 - sbins[2 * o + 1];
        float contrib = v * __expf(-(dx * dx + dy * dy) * (1.0f / 4.5f));
        contrib += __shfl_xor(contrib, 8);
        contrib += __shfl_xor(contrib, 16);
        contrib += __shfl_xor(contrib, 32);
        if ((lane >> 3) == 0) atomicAdd(&shb[o], contrib);
    }
    __syncthreads();
    if (t < KOb)
        atomicAdd(ws + WS_HBP + b * (NSLOT * KOb) + (R & (NSLOT - 1)) * KOb + t,
                  shb[t]);
}

// =====================================================================
// K1b: single-block Hbins finalize — reduce HBP (16 KB, L2-hot),
// softmax -> Wsoft, Wmean, write the 1 KB float4 table. ~launch cost.
// =====================================================================
__global__ __launch_bounds__(256) void k_hb(const float* __restrict__ bins,
                                            float* __restrict__ ws) {
    __shared__ float sred[64];
    const int t = threadIdx.x;
    if (t < 64) sred[t] = 0.f;
    __syncthreads();
    {
        const int p = t & 63, g = t >> 6;   // pair p = b*32+o, 4 slot-groups
        const int bb = p >> 5, oo = p & 31;
        float sum = 0.f;
        #pragma unroll
        for (int s = 0; s < 16; ++s)
            sum += ws[WS_HBP + bb * (NSLOT * KOb) + (g * 16 + s) * KOb + oo];
        atomicAdd(&sred[p], sum);
    }
    __syncthreads();
    if (t < 64) {
        const int oo = t & 31;
        const float h = 8.0f * sred[t];
        float mx = h;
        #pragma unroll
        for (int m = 16; m >= 1; m >>= 1) mx = fmaxf(mx, __shfl_xor(mx, m));
        const float e2 = __expf(h - mx);
        float ss = e2;
        #pragma unroll
        for (int m = 16; m >= 1; m >>= 1) ss += __shfl_xor(ss, m);
        const float wsf = e2 / ss;
        const float wm = 0.5f * (wsf + __shfl_xor(wsf, 32));
        ((float4*)(ws + WS_TBL))[t] =
            make_float4(bins[2 * oo], bins[2 * oo + 1], wsf, wm);
    }
}

// =====================================================================
// K2: per-row R_edges -> A1 -> entropy -> U, m; also chi. Wsoft/Wmean
// table precomputed by k_hb — just load 64 float4s.
// 2 rows per wave (all 64 lanes active).
// =====================================================================
__global__ __launch_bounds__(256) void k_row1(float* __restrict__ ws,
                                              float* __restrict__ out_u) {
    __shared__ float4 stbl[BB * KOb];   // {bin_x, bin_y, wsoft[b][o], wmean[o]}
    const int t = threadIdx.x;
    if (t < BB * KOb) stbl[t] = ((const float4*)(ws + WS_TBL))[t];
    __syncthreads();

    const int wv = t >> 6, lane = t & 63;
    const int half = lane >> 5, k = lane & 31;
    const int R = blockIdx.x * 8 + wv * 2 + half;
    const int b = R >> 12;
    const int r = R & (NN - 1);

    const float val = ws[WS_VALS + (size_t)R * KK + k];
    const int c = ((int*)(ws + WS_IDX))[(size_t)R * KK + k];
    const float dx0 = (float)((c & 63) - (r & 63));
    const float dy0 = (float)((c >> 6) - (r >> 6));
    float racc = 0.f, cacc = 0.f;
    const float4* tb = stbl + (b << 5);
    #pragma unroll
    for (int o = 0; o < KOb; ++o) {
        const float4 cb = tb[o];
        const float dx = dx0 - cb.x, dy = dy0 - cb.y;
        const float kap = __expf(-(dx * dx + dy * dy) * (1.0f / 4.5f));
        racc += cb.z * kap;
        cacc += cb.w * kap;
    }
    const float Redge = 0.001f + racc;
    const float chi = cacc;

    const float tilde = val * Redge;
    float s = tilde;
    #pragma unroll
    for (int m = 16; m >= 1; m >>= 1) s += __shfl_xor(s, m);
    const float a1 = tilde / (s + EPS);

    const float z = 10.f * a1;
    float mz = z;
    #pragma unroll
    for (int m = 16; m >= 1; m >>= 1) mz = fmaxf(mz, __shfl_xor(mz, m));
    const float e = __expf(z - mz);
    float se = e;
    #pragma unroll
    for (int m = 16; m >= 1; m >>= 1) se += __shfl_xor(se, m);
    const float p = e / se;
    const float ent_t = -p * __logf(p + EPS);
    float ent = ent_t;
    #pragma unroll
    for (int m = 16; m >= 1; m >>= 1) ent += __shfl_xor(ent, m);
    const float U = 1.f / (1.f + __expf(ent));

    ws[WS_A1  + (size_t)R * KK + k] = a1;
    ws[WS_CHI + (size_t)R * KK + k] = chi;
    if (k == 0) { out_u[R] = U; ws[WS_M + R] = 1.f - U; }
}

// =====================================================================
// K3: fused row2 + dense write. One block per row: wave 0 does the
// math (hatA -> A2_edges -> dv, q) holding dv,c in regs across the
// zero-fill barrier, scatters directly, whole block streams the dense
// row (nontemporal). Also zero-fills WS_TEV (blocks 0..31).
// =====================================================================
__global__ __launch_bounds__(256) void k_row2d(float* __restrict__ ws,
                                               float* __restrict__ outA2) {
    __shared__ float srow[NN];
    const int R = blockIdx.x;
    const int b = R >> 12;
    const int t = threadIdx.x;

    const int gid = blockIdx.x * 256 + t;
    if (gid < BB * NN) ws[WS_TEV + gid] = 0.f;

    nfloat4* s4 = (nfloat4*)srow;
    const nfloat4 z4 = {0.f, 0.f, 0.f, 0.f};
    #pragma unroll
    for (int i = 0; i < 4; ++i) s4[t + 256 * i] = z4;

    float dvr = 0.f; int cr = -1;
    if (t < 64) {
        const int lane = t;
        const bool act = lane < 32;
        const int k = lane;
        const float mi = ws[WS_M + R];
        float a1 = 0.f; int c = 0; float mj = 0.f;
        if (act) {
            a1 = ws[WS_A1 + (size_t)R * KK + k];
            c = ((int*)(ws + WS_IDX))[(size_t)R * KK + k];
            mj = ws[WS_M + b * NN + c];
        }
        const float hat = act ? mi * a1 * mj : 0.f;
        float S = hat;
        #pragma unroll
        for (int m = 16; m >= 1; m >>= 1) S += __shfl_xor(S, m);
        const float a2e = hat / (S + EPS);
        float S2 = a2e;
        #pragma unroll
        for (int m = 16; m >= 1; m >>= 1) S2 += __shfl_xor(S2, m);
        const float dv = a2e / (S2 + EPS);

        const float z = act ? 8.f * a2e : -1e30f;
        float mz = z;
        #pragma unroll
        for (int m = 16; m >= 1; m >>= 1) mz = fmaxf(mz, __shfl_xor(mz, m));
        const float e = act ? __expf(z - mz) : 0.f;
        float se = e;
        #pragma unroll
        for (int m = 16; m >= 1; m >>= 1) se += __shfl_xor(se, m);
        const float wl = e / se;
        const float chi = act ? ws[WS_CHI + (size_t)R * KK + k] : 0.f;
        float q = act ? wl * chi : 0.f;
        #pragma unroll
        for (int m = 16; m >= 1; m >>= 1) q += __shfl_xor(q, m);
        if (lane == 0) ws[WS_Q + R] = q;

        if (act) {
            ws[WS_A2 + (size_t)R * KK + k] = dv;
            dvr = dv; cr = c;
        }
    }
    __syncthreads();
    if (cr >= 0) srow[cr] = dvr;
    __syncthreads();
    nfloat4* o4 = (nfloat4*)(outA2 + (size_t)R * NN);
    #pragma unroll
    for (int i = 0; i < 4; ++i)
        __builtin_nontemporal_store(s4[t + 256 * i], o4 + t + 256 * i);
}

// =====================================================================
// K4: directional evidence — reverse value found by searching row c's
// 32 indices in the L2-resident edge arrays (2 MB).
// 2 rows per wave — all 64 lanes active.
// =====================================================================
__global__ __launch_bounds__(256) void k_dir(float* __restrict__ ws) {
    const int t = threadIdx.x;
    const int wv = t >> 6, lane = t & 63;
    const int half = lane >> 5, k = lane & 31;
    const int R = blockIdx.x * 8 + wv * 2 + half;
    const int b = R >> 12;
    const int r = R & (NN - 1);

    const float a = ws[WS_A2 + (size_t)R * KK + k];
    const int c = ((int*)(ws + WS_IDX))[(size_t)R * KK + k];
    float pdir = 0.f;
    if (c != r) {
        const int4* irow = (const int4*)((const int*)(ws + WS_IDX)
                                         + (size_t)(b * NN + c) * KK);
        int p = -1;
        #pragma unroll
        for (int q = 0; q < 8; ++q) {
            const int4 i4 = irow[q];
            if (i4.x == r) p = q * 4 + 0;
            if (i4.y == r) p = q * 4 + 1;
            if (i4.z == r) p = q * 4 + 2;
            if (i4.w == r) p = q * 4 + 3;
        }
        const float arev = (p >= 0) ? ws[WS_A2 + (size_t)(b * NN + c) * KK + p] : 0.f;
        const float ef = __expf(8.f * a), er = __expf(8.f * arev);
        pdir = ef / (ef + er + EPS);
    }
    float s = a * pdir;
    #pragma unroll
    for (int m = 16; m >= 1; m >>= 1) s += __shfl_xor(s, m);
    if (k == 0) ws[WS_SEV + R] = s;
    atomicAdd(ws + WS_TEV + b * NN + c, a * (1.f - pdir));
}

// =====================================================================
// K5: fused pi_src/pi_tgt + 5x5 gaussian smoothing + sigmoid.
// =====================================================================
__global__ void k_tail(const float* __restrict__ ws, const float* __restrict__ kern,
                       float* __restrict__ out_psrc, float* __restrict__ out_ptgt,
                       float* __restrict__ out_map) {
    const int i = blockIdx.x * 256 + threadIdx.x;
    const float s = ws[WS_SEV + i], tv = ws[WS_TEV + i];
    const float ps = s / (s + tv + EPS);
    out_psrc[i] = ps;
    out_ptgt[i] = 1.f - ps;

    const int b = i >> 12;
    const int pix = i & 4095;
    const int y = pix >> 6, x = pix & 63;
    float acc = 0.f;
    #pragma unroll
    for (int ky = 0; ky < 5; ++ky) {
        const int yy = y + ky - 2;
        if (yy < 0 || yy >= 64) continue;
        #pragma unroll
        for (int kx = 0; kx < 5; ++kx) {
            const int xx = x + kx - 2;
            if (xx < 0 || xx >= 64) continue;
            acc += ws[WS_Q + b * 4096 + yy * 64 + xx] * kern[ky * 5 + kx];
        }
    }
    out_map[i] = 1.f / (1.f + __expf(-acc));
}

extern "C" void kernel_launch(void* const* d_in, const int* in_sizes, int n_in,
                              void* d_out, int out_size, void* d_ws, size_t ws_size,
                              hipStream_t stream) {
    const float* A0   = (const float*)d_in[1];
    const float* bins = (const float*)d_in[3];
    const float* kern = (const float*)d_in[4];
    float* out = (float*)d_out;
    float* ws  = (float*)d_ws;

    (void)hipMemsetAsync(ws + WS_HBP, 0, BB * NSLOT * KOb * sizeof(float), stream);

    k_topk <<<BB * NN,       256, 0, stream>>>(A0, bins, ws);
    k_hb   <<<1,             256, 0, stream>>>(bins, ws);
    k_row1 <<<BB * NN / 8,   256, 0, stream>>>(ws, out + OUT_U);
    k_row2d<<<BB * NN,       256, 0, stream>>>(ws, out);
    k_dir  <<<BB * NN / 8,   256, 0, stream>>>(ws);
    k_tail <<<BB * NN / 256, 256, 0, stream>>>(ws, kern,
                                               out + OUT_PSRC, out + OUT_PTGT,
                                               out + OUT_MAP);
}

// Round 6
// 275.513 us; speedup vs baseline: 2.0167x; 1.0398x over previous
//
#include <hip/hip_runtime.h>
#include <math.h>

#define NN 4096
#define KK 32
#define KOb 32
#define BB 2
#define NSLOT 64   // Hbins partial slots (bounds global atomic contention)

constexpr float EPS = 1e-6f;

typedef float nfloat4 __attribute__((ext_vector_type(4)));  // native vec for NT builtins

// ---- workspace layout (in float elements) ----
#define WS_VALS   0                          // B*N*K floats
#define WS_IDX    (WS_VALS + BB*NN*KK)       // B*N*K ints
#define WS_HBP    (WS_IDX + BB*NN*KK)        // B*NSLOT*KO partials (memset 0)
#define WS_TBL    (WS_HBP + BB*NSLOT*KOb)    // BB*KO float4: {bx,by,wsoft,wmean}
#define WS_A1     (WS_TBL + BB*KOb*4)        // B*N*K
#define WS_M      (WS_A1 + BB*NN*KK)         // B*N
#define WS_CHI    (WS_M + BB*NN)             // B*N*K
#define WS_A2     (WS_CHI + BB*NN*KK)        // B*N*K
#define WS_SEV    (WS_A2 + BB*NN*KK)         // B*N
#define WS_TEV    (WS_SEV + BB*NN)           // B*N (zeroed in k_row2m)
#define WS_Q      (WS_TEV + BB*NN)           // B*N

// ---- output layout (float elements) ----
#define OUT_A2   0
#define OUT_U    ((size_t)BB*NN*NN)
#define OUT_PSRC (OUT_U + BB*NN)
#define OUT_PTGT (OUT_PSRC + BB*NN)
#define OUT_MAP  (OUT_PTGT + BB*NN)

__device__ __forceinline__ unsigned int fkey(float x) {
    unsigned int u = __float_as_uint(x);
    return u ^ ((unsigned int)((int)u >> 31) | 0x80000000u);
}
__device__ __forceinline__ float key2f(unsigned int k) {
    unsigned int u = (k & 0x80000000u) ? (k ^ 0x80000000u) : ~k;
    return __uint_as_float(u);
}

// =====================================================================
// K1: per-row top-32, ONE 256-thread BLOCK per row. 16 keys/lane in
// registers (nontemporal: A0 is read-once), block threshold search
// (1 barrier/iter via double-buffered counts), prefix compaction,
// wave0 rank-select, fused Hbins. NO per-block device fence/counter
// (R4 lesson: 8192 same-address atomics serialize ≈ +240 µs).
// =====================================================================
__global__ __launch_bounds__(256) void k_topk(const float* __restrict__ A0,
                                              const float* __restrict__ bins,
                                              float* __restrict__ ws) {
    __shared__ float sbins[2 * KOb];
    __shared__ int   scnt[2][4];
    __shared__ int   swtot[4];
    __shared__ unsigned long long cand[64];
    __shared__ float selv[KK], seldx[KK], seldy[KK];
    __shared__ float shb[KOb];

    const int t = threadIdx.x;
    const int wv = t >> 6, lane = t & 63;
    const int R = blockIdx.x;
    const int b = R >> 12;
    const int r = R & (NN - 1);

    if (t < 2 * KOb) sbins[t] = bins[t];
    if (t < KOb) shb[t] = 0.f;

    // coalesced: thread t reads float4 #(i*256+t); elem of key[4i+c] = i*1024 + t*4 + c
    const nfloat4* row4 = (const nfloat4*)(A0 + (size_t)R * NN);
    unsigned int key[16];
    #pragma unroll
    for (int i = 0; i < 4; ++i) {
        const nfloat4 f = __builtin_nontemporal_load(row4 + i * 256 + t);
        key[4 * i + 0] = fkey(f.x);
        key[4 * i + 1] = fkey(f.y);
        key[4 * i + 2] = fkey(f.z);
        key[4 * i + 3] = fkey(f.w);
    }

    // ---- block-uniform threshold search: 32 <= count(key > lo) <= 64 ----
    unsigned int lo = 0u, hi = 0xFFFFFFFFu;
    int cnt = NN, it = 0;
    while (cnt > 64) {
        unsigned int mid;
        if (it == 0)      mid = 0xBF7E0000u;   // fkey(0.9921875) ~ E[cnt]=32
        else if (it == 1) mid = 0xBF7C4000u;   // fkey(0.98535)  ~ E[cnt]=60
        else              mid = lo + ((hi - lo) >> 1);
        if (mid <= lo || mid >= hi) mid = lo + ((hi - lo) >> 1);
        if (mid == lo) break;
        int cl = 0;
        #pragma unroll
        for (int j = 0; j < 16; ++j) cl += (key[j] > mid) ? 1 : 0;
        int c = cl;
        #pragma unroll
        for (int m = 32; m >= 1; m >>= 1) c += __shfl_xor(c, m);
        const int p = it & 1;
        if (lane == 0) scnt[p][wv] = c;
        __syncthreads();
        const int ctot = scnt[p][0] + scnt[p][1] + scnt[p][2] + scnt[p][3];
        if (ctot >= KK) { lo = mid; cnt = ctot; } else hi = mid;
        if (++it > 48) break;
    }

    // ---- block prefix compaction of candidates {key > lo} ----
    int cl = 0;
    #pragma unroll
    for (int j = 0; j < 16; ++j) cl += (key[j] > lo) ? 1 : 0;
    int inc = cl;
    #pragma unroll
    for (int m = 1; m < 64; m <<= 1) {
        const int o = __shfl_up(inc, m);
        if (lane >= m) inc += o;
    }
    if (lane == 63) swtot[wv] = inc;
    __syncthreads();
    int off = inc - cl;                        // exclusive within wave
    #pragma unroll
    for (int w = 0; w < 4; ++w) if (w < wv) off += swtot[w];
    const int nc0 = swtot[0] + swtot[1] + swtot[2] + swtot[3];
    const int ncand = (nc0 < 64) ? nc0 : 64;

    int slot = off;
    #pragma unroll
    for (int j = 0; j < 16; ++j) {
        if (key[j] > lo && slot < 64) {
            const unsigned int gidx = (unsigned int)((j >> 2) * 1024 + t * 4 + (j & 3));
            cand[slot] = ((unsigned long long)key[j] << 32)
                       | (unsigned long long)(4095u - gidx);
            ++slot;
        }
    }
    __syncthreads();

    // ---- wave 0: rank selection + emit; packed u64 gives exact tie-break ----
    if (t < 64) {
        const unsigned long long cd = (t < ncand) ? cand[t] : 0ull;
        int rank = 0;
        #pragma unroll
        for (int i = 0; i < 64; ++i) {
            const unsigned long long o = __shfl(cd, i);
            rank += (o > cd) ? 1 : 0;
        }
        if (t < ncand && rank < KK) {
            const float val = key2f((unsigned int)(cd >> 32));
            const int gidx = 4095 - (int)(cd & 0xFFFull);
            ws[WS_VALS + (size_t)R * KK + rank] = val;
            ((int*)(ws + WS_IDX))[(size_t)R * KK + rank] = gidx;
            selv[rank]  = val;
            seldx[rank] = (float)((gidx & 63) - (r & 63));
            seldy[rank] = (float)((gidx >> 6) - (r >> 6));
        }
    }
    __syncthreads();

    // ---- fused Hbins: 32 edges x 32 bins = 1024 tasks over 256 threads ----
    const int e = t >> 3;                       // edge 0..31
    const float v = selv[e], dx0 = seldx[e], dy0 = seldy[e];
    #pragma unroll
    for (int jj = 0; jj < 4; ++jj) {
        const int o = (lane & 7) * 4 + jj;      // bin, constant across xor-8/16/32 group
        const float dx = dx0 - sbins[2 * o], dy = dy0 - sbins[2 * o + 1];
        float contrib = v * __expf(-(dx * dx + dy * dy) * (1.0f / 4.5f));
        contrib += __shfl_xor(contrib, 8);
        contrib += __shfl_xor(contrib, 16);
        contrib += __shfl_xor(contrib, 32);
        if ((lane >> 3) == 0) atomicAdd(&shb[o], contrib);
    }
    __syncthreads();
    if (t < KOb)
        atomicAdd(ws + WS_HBP + b * (NSLOT * KOb) + (R & (NSLOT - 1)) * KOb + t,
                  shb[t]);
}

// =====================================================================
// K1b: single-block Hbins finalize — reduce HBP (16 KB, L2-hot),
// softmax -> Wsoft, Wmean, write the 1 KB float4 table. ~launch cost.
// =====================================================================
__global__ __launch_bounds__(256) void k_hb(const float* __restrict__ bins,
                                            float* __restrict__ ws) {
    __shared__ float sred[64];
    const int t = threadIdx.x;
    if (t < 64) sred[t] = 0.f;
    __syncthreads();
    {
        const int p = t & 63, g = t >> 6;   // pair p = b*32+o, 4 slot-groups
        const int bb = p >> 5, oo = p & 31;
        float sum = 0.f;
        #pragma unroll
        for (int s = 0; s < 16; ++s)
            sum += ws[WS_HBP + bb * (NSLOT * KOb) + (g * 16 + s) * KOb + oo];
        atomicAdd(&sred[p], sum);
    }
    __syncthreads();
    if (t < 64) {
        const int oo = t & 31;
        const float h = 8.0f * sred[t];
        float mx = h;
        #pragma unroll
        for (int m = 16; m >= 1; m >>= 1) mx = fmaxf(mx, __shfl_xor(mx, m));
        const float e2 = __expf(h - mx);
        float ss = e2;
        #pragma unroll
        for (int m = 16; m >= 1; m >>= 1) ss += __shfl_xor(ss, m);
        const float wsf = e2 / ss;
        const float wm = 0.5f * (wsf + __shfl_xor(wsf, 32));
        ((float4*)(ws + WS_TBL))[t] =
            make_float4(bins[2 * oo], bins[2 * oo + 1], wsf, wm);
    }
}

// =====================================================================
// K2: per-row R_edges -> A1 -> entropy -> U, m; also chi. Wsoft/Wmean
// table precomputed by k_hb — just load 64 float4s.
// 2 rows per wave (all 64 lanes active).
// =====================================================================
__global__ __launch_bounds__(256) void k_row1(float* __restrict__ ws,
                                              float* __restrict__ out_u) {
    __shared__ float4 stbl[BB * KOb];   // {bin_x, bin_y, wsoft[b][o], wmean[o]}
    const int t = threadIdx.x;
    if (t < BB * KOb) stbl[t] = ((const float4*)(ws + WS_TBL))[t];
    __syncthreads();

    const int wv = t >> 6, lane = t & 63;
    const int half = lane >> 5, k = lane & 31;
    const int R = blockIdx.x * 8 + wv * 2 + half;
    const int b = R >> 12;
    const int r = R & (NN - 1);

    const float val = ws[WS_VALS + (size_t)R * KK + k];
    const int c = ((int*)(ws + WS_IDX))[(size_t)R * KK + k];
    const float dx0 = (float)((c & 63) - (r & 63));
    const float dy0 = (float)((c >> 6) - (r >> 6));
    float racc = 0.f, cacc = 0.f;
    const float4* tb = stbl + (b << 5);
    #pragma unroll
    for (int o = 0; o < KOb; ++o) {
        const float4 cb = tb[o];
        const float dx = dx0 - cb.x, dy = dy0 - cb.y;
        const float kap = __expf(-(dx * dx + dy * dy) * (1.0f / 4.5f));
        racc += cb.z * kap;
        cacc += cb.w * kap;
    }
    const float Redge = 0.001f + racc;
    const float chi = cacc;

    const float tilde = val * Redge;
    float s = tilde;
    #pragma unroll
    for (int m = 16; m >= 1; m >>= 1) s += __shfl_xor(s, m);
    const float a1 = tilde / (s + EPS);

    const float z = 10.f * a1;
    float mz = z;
    #pragma unroll
    for (int m = 16; m >= 1; m >>= 1) mz = fmaxf(mz, __shfl_xor(mz, m));
    const float e = __expf(z - mz);
    float se = e;
    #pragma unroll
    for (int m = 16; m >= 1; m >>= 1) se += __shfl_xor(se, m);
    const float p = e / se;
    const float ent_t = -p * __logf(p + EPS);
    float ent = ent_t;
    #pragma unroll
    for (int m = 16; m >= 1; m >>= 1) ent += __shfl_xor(ent, m);
    const float U = 1.f / (1.f + __expf(ent));

    ws[WS_A1  + (size_t)R * KK + k] = a1;
    ws[WS_CHI + (size_t)R * KK + k] = chi;
    if (k == 0) { out_u[R] = U; ws[WS_M + R] = 1.f - U; }
}

// =====================================================================
// K3: row2 MATH only — hatA -> A2_edges -> dv, q. 2 rows/wave, all 64
// lanes active (was half-wave idle in the old fused kernel).
// Also zero-fills WS_TEV.
// =====================================================================
__global__ __launch_bounds__(256) void k_row2m(float* __restrict__ ws) {
    const int t = threadIdx.x;
    const int gid = blockIdx.x * 256 + t;
    if (gid < BB * NN) ws[WS_TEV + gid] = 0.f;

    const int wv = t >> 6, lane = t & 63;
    const int half = lane >> 5, k = lane & 31;
    const int R = blockIdx.x * 8 + wv * 2 + half;
    const int b = R >> 12;

    const float mi = ws[WS_M + R];
    const float a1 = ws[WS_A1 + (size_t)R * KK + k];
    const int c = ((int*)(ws + WS_IDX))[(size_t)R * KK + k];
    const float mj = ws[WS_M + b * NN + c];

    const float hat = mi * a1 * mj;
    float S = hat;
    #pragma unroll
    for (int m = 16; m >= 1; m >>= 1) S += __shfl_xor(S, m);
    const float a2e = hat / (S + EPS);
    float S2 = a2e;
    #pragma unroll
    for (int m = 16; m >= 1; m >>= 1) S2 += __shfl_xor(S2, m);
    const float dv = a2e / (S2 + EPS);

    const float z = 8.f * a2e;
    float mz = z;
    #pragma unroll
    for (int m = 16; m >= 1; m >>= 1) mz = fmaxf(mz, __shfl_xor(mz, m));
    const float e = __expf(z - mz);
    float se = e;
    #pragma unroll
    for (int m = 16; m >= 1; m >>= 1) se += __shfl_xor(se, m);
    const float wl = e / se;
    const float chi = ws[WS_CHI + (size_t)R * KK + k];
    float q = wl * chi;
    #pragma unroll
    for (int m = 16; m >= 1; m >>= 1) q += __shfl_xor(q, m);

    ws[WS_A2 + (size_t)R * KK + k] = dv;
    if (k == 0) ws[WS_Q + R] = q;
}

// =====================================================================
// K4: FUSED directional evidence + dense-row write. One block per row:
// lanes 0-31 do the dir math (latency-bound: L2 irow search + scattered
// TEV atomics) while the whole block streams the 16 KB dense row
// (BW-bound NT stores) — complementary pipes overlapped.
// =====================================================================
__global__ __launch_bounds__(256) void k_dirw(float* __restrict__ ws,
                                              float* __restrict__ outA2) {
    __shared__ float srow[NN];
    const int R = blockIdx.x;
    const int b = R >> 12;
    const int r = R & (NN - 1);
    const int t = threadIdx.x;

    nfloat4* s4 = (nfloat4*)srow;
    const nfloat4 z4 = {0.f, 0.f, 0.f, 0.f};
    #pragma unroll
    for (int i = 0; i < 4; ++i) s4[t + 256 * i] = z4;

    float dvr = 0.f; int cr = -1;
    if (t < 32) {
        const int k = t;
        const float a = ws[WS_A2 + (size_t)R * KK + k];   // = dv (A2 edge value)
        const int c = ((int*)(ws + WS_IDX))[(size_t)R * KK + k];
        float pdir = 0.f;
        if (c != r) {
            const int4* irow = (const int4*)((const int*)(ws + WS_IDX)
                                             + (size_t)(b * NN + c) * KK);
            int p = -1;
            #pragma unroll
            for (int q = 0; q < 8; ++q) {
                const int4 i4 = irow[q];
                if (i4.x == r) p = q * 4 + 0;
                if (i4.y == r) p = q * 4 + 1;
                if (i4.z == r) p = q * 4 + 2;
                if (i4.w == r) p = q * 4 + 3;
            }
            const float arev = (p >= 0) ? ws[WS_A2 + (size_t)(b * NN + c) * KK + p] : 0.f;
            const float ef = __expf(8.f * a), er = __expf(8.f * arev);
            pdir = ef / (ef + er + EPS);
        }
        float s = a * pdir;
        #pragma unroll
        for (int m = 16; m >= 1; m >>= 1) s += __shfl_xor(s, m);
        if (k == 0) ws[WS_SEV + R] = s;
        atomicAdd(ws + WS_TEV + b * NN + c, a * (1.f - pdir));
        dvr = a; cr = c;
    }
    __syncthreads();
    if (cr >= 0) srow[cr] = dvr;
    __syncthreads();
    nfloat4* o4 = (nfloat4*)(outA2 + (size_t)R * NN);
    #pragma unroll
    for (int i = 0; i < 4; ++i)
        __builtin_nontemporal_store(s4[t + 256 * i], o4 + t + 256 * i);
}

// =====================================================================
// K5: fused pi_src/pi_tgt + 5x5 gaussian smoothing + sigmoid.
// =====================================================================
__global__ void k_tail(const float* __restrict__ ws, const float* __restrict__ kern,
                       float* __restrict__ out_psrc, float* __restrict__ out_ptgt,
                       float* __restrict__ out_map) {
    const int i = blockIdx.x * 256 + threadIdx.x;
    const float s = ws[WS_SEV + i], tv = ws[WS_TEV + i];
    const float ps = s / (s + tv + EPS);
    out_psrc[i] = ps;
    out_ptgt[i] = 1.f - ps;

    const int b = i >> 12;
    const int pix = i & 4095;
    const int y = pix >> 6, x = pix & 63;
    float acc = 0.f;
    #pragma unroll
    for (int ky = 0; ky < 5; ++ky) {
        const int yy = y + ky - 2;
        if (yy < 0 || yy >= 64) continue;
        #pragma unroll
        for (int kx = 0; kx < 5; ++kx) {
            const int xx = x + kx - 2;
            if (xx < 0 || xx >= 64) continue;
            acc += ws[WS_Q + b * 4096 + yy * 64 + xx] * kern[ky * 5 + kx];
        }
    }
    out_map[i] = 1.f / (1.f + __expf(-acc));
}

extern "C" void kernel_launch(void* const* d_in, const int* in_sizes, int n_in,
                              void* d_out, int out_size, void* d_ws, size_t ws_size,
                              hipStream_t stream) {
    const float* A0   = (const float*)d_in[1];
    const float* bins = (const float*)d_in[3];
    const float* kern = (const float*)d_in[4];
    float* out = (float*)d_out;
    float* ws  = (float*)d_ws;

    (void)hipMemsetAsync(ws + WS_HBP, 0, BB * NSLOT * KOb * sizeof(float), stream);

    k_topk <<<BB * NN,       256, 0, stream>>>(A0, bins, ws);
    k_hb   <<<1,             256, 0, stream>>>(bins, ws);
    k_row1 <<<BB * NN / 8,   256, 0, stream>>>(ws, out + OUT_U);
    k_row2m<<<BB * NN / 8,   256, 0, stream>>>(ws);
    k_dirw <<<BB * NN,       256, 0, stream>>>(ws, out);
    k_tail <<<BB * NN / 256, 256, 0, stream>>>(ws, kern,
                                               out + OUT_PSRC, out + OUT_PTGT,
                                               out + OUT_MAP);
}